// Round 1
// baseline (38339.111 us; speedup 1.0000x reference)
//
#include <hip/hip_runtime.h>
#include <hip/hip_bf16.h>
#include <hip/hip_cooperative_groups.h>
#include <cstddef>
#include <cstdint>

namespace cg = cooperative_groups;

static constexpr int BB = 16;    // batch
static constexpr int TT = 1024;  // time steps
static constexpr int EE = 512;   // input dim
static constexpr int HH = 1024;  // hidden dim

// ---------- storage-type helpers (fp32 or bf16 scratch for xr/xz) ----------
__device__ __forceinline__ float st_load(const float* p) { return *p; }
__device__ __forceinline__ float st_load(const __hip_bfloat16* p) { return __bfloat162float(*p); }
__device__ __forceinline__ void st_store(float* p, float v) { *p = v; }
__device__ __forceinline__ void st_store(__hip_bfloat16* p, float v) { *p = __float2bfloat16(v); }

#define FMA4(ACC, S, W)                         \
    (ACC).x = fmaf((S), (W).x, (ACC).x);        \
    (ACC).y = fmaf((S), (W).y, (ACC).y);        \
    (ACC).z = fmaf((S), (W).z, (ACC).z);        \
    (ACC).w = fmaf((S), (W).w, (ACC).w);

// =====================================================================
// Phase 1: xr = x@Wxr+br -> ws, xz = x@Wxz+bz -> ws, xi = x@Wi+b -> d_out
// Fused 3-output fp32 GEMM, M=16384, K=512, N=1024. Tile 64x64, BK=16.
// x tile stored TRANSPOSED in LDS so A-fragments are float4 reads.
// =====================================================================
template <typename ST>
__global__ __launch_bounds__(256) void proj_kernel(
    const float* __restrict__ x,
    const float* __restrict__ Wxr, const float* __restrict__ br,
    const float* __restrict__ Wxz, const float* __restrict__ bz,
    const float* __restrict__ Wi,  const float* __restrict__ bi,
    ST* __restrict__ xr_out, ST* __restrict__ xz_out, float* __restrict__ xi_out)
{
    __shared__ float xT[16][68];      // [k][m] transposed x tile (+4 pad keeps float4 aligned)
    __shared__ float wB[3][16][64];   // [gate][k][n]

    const int tid = threadIdx.x;
    const int tx = tid & 15, ty = tid >> 4;
    const int m0 = blockIdx.y * 64, n0 = blockIdx.x * 64;
    const float* Wg[3] = {Wxr, Wxz, Wi};

    float4 acc[3][4];
#pragma unroll
    for (int g = 0; g < 3; ++g)
#pragma unroll
        for (int i = 0; i < 4; ++i) acc[g][i] = make_float4(0.f, 0.f, 0.f, 0.f);

    const int xrow = tid >> 2, xk = (tid & 3) * 4;   // x stage: 64 rows x 16 k
    const int wk = tid >> 4, wn = (tid & 15) * 4;    // W stage: 16 k x 64 n

    for (int k0 = 0; k0 < EE; k0 += 16) {
        float4 xv = *(const float4*)(x + (size_t)(m0 + xrow) * EE + k0 + xk);
        xT[xk + 0][xrow] = xv.x;
        xT[xk + 1][xrow] = xv.y;
        xT[xk + 2][xrow] = xv.z;
        xT[xk + 3][xrow] = xv.w;
#pragma unroll
        for (int g = 0; g < 3; ++g) {
            float4 wv = *(const float4*)(Wg[g] + (size_t)(k0 + wk) * HH + n0 + wn);
            *(float4*)&wB[g][wk][wn] = wv;
        }
        __syncthreads();
#pragma unroll
        for (int kk = 0; kk < 16; ++kk) {
            float4 a  = *(const float4*)&xT[kk][ty * 4];
            float4 w0 = *(const float4*)&wB[0][kk][tx * 4];
            float4 w1 = *(const float4*)&wB[1][kk][tx * 4];
            float4 w2 = *(const float4*)&wB[2][kk][tx * 4];
            float as[4] = {a.x, a.y, a.z, a.w};
#pragma unroll
            for (int i = 0; i < 4; ++i) {
                FMA4(acc[0][i], as[i], w0);
                FMA4(acc[1][i], as[i], w1);
                FMA4(acc[2][i], as[i], w2);
            }
        }
        __syncthreads();
    }

    float4 bv0 = *(const float4*)(br + n0 + tx * 4);
    float4 bv1 = *(const float4*)(bz + n0 + tx * 4);
    float4 bv2 = *(const float4*)(bi + n0 + tx * 4);
#pragma unroll
    for (int i = 0; i < 4; ++i) {
        size_t m = (size_t)m0 + ty * 4 + i;
        size_t off = m * HH + n0 + tx * 4;
        float4 v0 = acc[0][i]; v0.x += bv0.x; v0.y += bv0.y; v0.z += bv0.z; v0.w += bv0.w;
        float4 v1 = acc[1][i]; v1.x += bv1.x; v1.y += bv1.y; v1.z += bv1.z; v1.w += bv1.w;
        float4 v2 = acc[2][i]; v2.x += bv2.x; v2.y += bv2.y; v2.z += bv2.z; v2.w += bv2.w;
        st_store(xr_out + off + 0, v0.x); st_store(xr_out + off + 1, v0.y);
        st_store(xr_out + off + 2, v0.z); st_store(xr_out + off + 3, v0.w);
        st_store(xz_out + off + 0, v1.x); st_store(xz_out + off + 1, v1.y);
        st_store(xz_out + off + 2, v1.z); st_store(xz_out + off + 3, v1.w);
        *(float4*)(xi_out + off) = v2;   // xi lives in d_out; overwritten with h later
    }
}

// =====================================================================
// DPP all-reduce over each row of 16 lanes (sum). xor1,xor2 via quad_perm,
// then rotate-by-4 and rotate-by-8 (rotation == xor for full reduction).
// =====================================================================
__device__ __forceinline__ float row16_allreduce(float v) {
    int y;
    y = __builtin_amdgcn_update_dpp(0, __float_as_int(v), 0xB1, 0xF, 0xF, true);  // quad_perm [1,0,3,2]
    v += __int_as_float(y);
    y = __builtin_amdgcn_update_dpp(0, __float_as_int(v), 0x4E, 0xF, 0xF, true);  // quad_perm [2,3,0,1]
    v += __int_as_float(y);
    y = __builtin_amdgcn_update_dpp(0, __float_as_int(v), 0x124, 0xF, 0xF, true); // row_ror:4
    v += __int_as_float(y);
    y = __builtin_amdgcn_update_dpp(0, __float_as_int(v), 0x128, 0xF, 0xF, true); // row_ror:8
    v += __int_as_float(y);
    return v;
}

// =====================================================================
// Phase 2: persistent cooperative scan. 256 blocks x 256 threads.
// Block owns 4 hidden columns (n0=bid*4) across all 3 gate matrices.
// Thread: lane = cg*16 + kslo ; cg in [0,4) covers gate-col units
// {cg*3+u : u<3}; k-slice ks = wave*16 + kslo covers k in [16ks,16ks+16).
// Weights register-resident: 48 fp32/thread (3 units x 4 float4).
// h ping-pongs through global hbuf; one grid.sync per step.
// =====================================================================
template <typename ST>
__global__ __launch_bounds__(256, 1) void scan_kernel(
    const ST* __restrict__ xr, const ST* __restrict__ xz,
    const float* __restrict__ Whr, const float* __restrict__ Whz, const float* __restrict__ Wh,
    float* __restrict__ out,      // d_out: holds xi pre-activations, overwritten with h
    float* __restrict__ hbuf)     // [2][16][1024] fp32
{
    cg::grid_group grid = cg::this_grid();

    __shared__ float4 hs[16 * 256];      // swizzled h (64 KB)
    __shared__ float red[4][4][48];      // [wave][cg][b*3+u]
    __shared__ float pre[12][16];        // [gate*4+c][b]

    const int tid = threadIdx.x, bid = blockIdx.x;
    const int lane = tid & 63, wv = tid >> 6;
    const int cgg = lane >> 4, kslo = lane & 15;
    const int ks = wv * 16 + kslo;       // 0..63, k in [16*ks, 16*ks+16)
    const int n0 = bid * 4;

    // ---- load recurrent weights into registers (one-time) ----
    float4 wreg[3][4];
    {
        const float* WG[3] = {Whr, Whz, Wh};
#pragma unroll
        for (int u = 0; u < 3; ++u) {
            int ugc = cgg * 3 + u;           // 0..11 == gate*4 + c
            const float* W = WG[ugc >> 2];
            int col = n0 + (ugc & 3);
#pragma unroll
            for (int j = 0; j < 4; ++j) {
                int kb = ks * 16 + j * 4;
                wreg[u][j] = make_float4(W[(size_t)(kb + 0) * HH + col],
                                         W[(size_t)(kb + 1) * HH + col],
                                         W[(size_t)(kb + 2) * HH + col],
                                         W[(size_t)(kb + 3) * HH + col]);
            }
        }
    }

    if (tid < 64) hbuf[bid * 64 + tid] = 0.f;   // zero h_0 (buffer 0)
    grid.sync();

    for (int t = 0; t < TT; ++t) {
        const float4* hin = (const float4*)(hbuf + (size_t)(t & 1) * (BB * HH));
        float* hout = hbuf + (size_t)((t + 1) & 1) * (BB * HH);

        // ---- stage h into LDS (XOR-swizzled float4 slots: 2-way banks) ----
#pragma unroll
        for (int i = 0; i < 16; ++i) {
            int q = tid + i * 256;           // b = q>>8, slot s = q&255
            float4 v = hin[q];
            int s = q & 255;
            hs[(q & ~255) | (s ^ ((s >> 3) & 7))] = v;
        }
        __syncthreads();

        // ---- partial dot products: 768 FMA/thread ----
        float pacc[16][3];
#pragma unroll
        for (int b = 0; b < 16; ++b)
#pragma unroll
            for (int u = 0; u < 3; ++u) pacc[b][u] = 0.f;

#pragma unroll
        for (int b = 0; b < 16; ++b) {
#pragma unroll
            for (int j = 0; j < 4; ++j) {
                int s = ks * 4 + j;
                float4 h4 = hs[(b << 8) | (s ^ ((s >> 3) & 7))];
#pragma unroll
                for (int u = 0; u < 3; ++u) {
                    pacc[b][u] = fmaf(h4.x, wreg[u][j].x, pacc[b][u]);
                    pacc[b][u] = fmaf(h4.y, wreg[u][j].y, pacc[b][u]);
                    pacc[b][u] = fmaf(h4.z, wreg[u][j].z, pacc[b][u]);
                    pacc[b][u] = fmaf(h4.w, wreg[u][j].w, pacc[b][u]);
                }
            }
        }

        // ---- reduce over the 16 k-sub-slices in each wave row ----
#pragma unroll
        for (int b = 0; b < 16; ++b)
#pragma unroll
            for (int u = 0; u < 3; ++u) pacc[b][u] = row16_allreduce(pacc[b][u]);

        if (kslo == 0) {
#pragma unroll
            for (int b = 0; b < 16; ++b)
#pragma unroll
                for (int u = 0; u < 3; ++u) red[wv][cgg][b * 3 + u] = pacc[b][u];
        }
        __syncthreads();

        // ---- combine the 4 waves -> gate pre-activations ----
        if (tid < 192) {
            int b = tid & 15, ugc = tid >> 4;      // ugc = gate*4 + c
            int cq = ugc / 3, u = ugc % 3;
            pre[ugc][b] = red[0][cq][b * 3 + u] + red[1][cq][b * 3 + u] +
                          red[2][cq][b * 3 + u] + red[3][cq][b * 3 + u];
        }
        __syncthreads();

        // ---- elementwise GRU update for this block's 4 columns ----
        if (tid < 64) {
            int c = tid & 3, b = tid >> 2;
            size_t idx = (size_t)(b * TT + t) * HH + n0 + c;
            float dr = pre[c][b], dz = pre[4 + c][b], dh = pre[8 + c][b];
            float r = 1.f / (1.f + expf(-(dr + st_load(xr + idx))));
            float z = 1.f / (1.f + expf(-(dz + st_load(xz + idx))));
            float cand = tanhf(fmaf(r, dh, out[idx]));            // out holds xi
            int sb = bid ^ ((bid >> 3) & 7);                      // swizzled slot of col group
            float4 h4 = hs[(b << 8) | sb];
            float hprev = (c == 0) ? h4.x : ((c == 1) ? h4.y : ((c == 2) ? h4.z : h4.w));
            float hnew = fmaf(z, hprev - cand, cand);             // z*h + (1-z)*cand
            out[idx] = hnew;
            hout[b * HH + n0 + c] = hnew;
        }
        grid.sync();
    }
}

__global__ void sentinel_kernel(float* out) {
    if (threadIdx.x == 0 && blockIdx.x == 0) out[0] = 12345.0f;  // ws too small marker
}

// =====================================================================
extern "C" void kernel_launch(void* const* d_in, const int* in_sizes, int n_in,
                              void* d_out, int out_size, void* d_ws, size_t ws_size,
                              hipStream_t stream) {
    const float* x   = (const float*)d_in[0];
    const float* Wxr = (const float*)d_in[1];
    const float* Whr = (const float*)d_in[2];
    const float* br  = (const float*)d_in[3];
    const float* Wxz = (const float*)d_in[4];
    const float* Whz = (const float*)d_in[5];
    const float* bz  = (const float*)d_in[6];
    const float* Wi  = (const float*)d_in[7];
    const float* Wh  = (const float*)d_in[8];
    const float* bb  = (const float*)d_in[9];
    float* out = (float*)d_out;

    const size_t BTH = (size_t)BB * TT * HH;       // 16.78M elements
    const size_t HBUF_BYTES = (size_t)2 * BB * HH * sizeof(float);
    const size_t need_f32 = 2 * BTH * sizeof(float) + HBUF_BYTES;
    const size_t need_b16 = 2 * BTH * sizeof(__hip_bfloat16) + HBUF_BYTES;

    dim3 pgrid(HH / 64, (BB * TT) / 64);   // (16, 256)

    if (ws_size >= need_f32) {
        float* xr = (float*)d_ws;
        float* xz = xr + BTH;
        float* hb = xz + BTH;
        proj_kernel<float><<<pgrid, 256, 0, stream>>>(x, Wxr, br, Wxz, bz, Wi, bb, xr, xz, out);
        const float* xrc = xr; const float* xzc = xz;
        void* args[7] = {(void*)&xrc, (void*)&xzc, (void*)&Whr, (void*)&Whz,
                         (void*)&Wh, (void*)&out, (void*)&hb};
        hipLaunchCooperativeKernel((void*)scan_kernel<float>, dim3(256), dim3(256),
                                   args, 0, stream);
    } else if (ws_size >= need_b16) {
        __hip_bfloat16* xr = (__hip_bfloat16*)d_ws;
        __hip_bfloat16* xz = xr + BTH;
        float* hb = (float*)(xz + BTH);
        proj_kernel<__hip_bfloat16><<<pgrid, 256, 0, stream>>>(x, Wxr, br, Wxz, bz, Wi, bb, xr, xz, out);
        const __hip_bfloat16* xrc = xr; const __hip_bfloat16* xzc = xz;
        void* args[7] = {(void*)&xrc, (void*)&xzc, (void*)&Whr, (void*)&Whz,
                         (void*)&Wh, (void*)&out, (void*)&hb};
        hipLaunchCooperativeKernel((void*)scan_kernel<__hip_bfloat16>, dim3(256), dim3(256),
                                   args, 0, stream);
    } else {
        sentinel_kernel<<<1, 64, 0, stream>>>(out);   // diagnosable failure mode
    }
}

// Round 2
// 10666.514 us; speedup vs baseline: 3.5943x; 3.5943x over previous
//
#include <hip/hip_runtime.h>
#include <hip/hip_bf16.h>
#include <cstddef>
#include <cstdint>

static constexpr int BB = 16;    // batch
static constexpr int TT = 1024;  // time steps
static constexpr int EE = 512;   // input dim
static constexpr int HH = 1024;  // hidden dim

using u32 = unsigned int;
using u64 = unsigned long long;

// ---------- storage-type helpers (fp32 or bf16 scratch for xr/xz) ----------
__device__ __forceinline__ float st_load(const float* p) { return *p; }
__device__ __forceinline__ float st_load(const __hip_bfloat16* p) { return __bfloat162float(*p); }
__device__ __forceinline__ void st_store(float* p, float v) { *p = v; }
__device__ __forceinline__ void st_store(__hip_bfloat16* p, float v) { *p = __float2bfloat16(v); }

#define FMA4(ACC, S, W)                         \
    (ACC).x = fmaf((S), (W).x, (ACC).x);        \
    (ACC).y = fmaf((S), (W).y, (ACC).y);        \
    (ACC).z = fmaf((S), (W).z, (ACC).z);        \
    (ACC).w = fmaf((S), (W).w, (ACC).w);

// =====================================================================
// Phase 1: xr = x@Wxr+br -> ws, xz = x@Wxz+bz -> ws, xi = x@Wi+b -> d_out
// Also zeroes the scan kernel's barrier counters (block 0).
// =====================================================================
template <typename ST>
__global__ __launch_bounds__(256) void proj_kernel(
    const float* __restrict__ x,
    const float* __restrict__ Wxr, const float* __restrict__ br,
    const float* __restrict__ Wxz, const float* __restrict__ bz,
    const float* __restrict__ Wi,  const float* __restrict__ bi,
    ST* __restrict__ xr_out, ST* __restrict__ xz_out, float* __restrict__ xi_out,
    u32* __restrict__ bar)
{
    __shared__ float xT[16][68];      // [k][m] transposed x tile
    __shared__ float wB[3][16][64];   // [gate][k][n]

    const int tid = threadIdx.x;
    if (blockIdx.x == 0 && blockIdx.y == 0 && tid < 17) bar[tid * 32] = 0u;  // 16 groups + root

    const int tx = tid & 15, ty = tid >> 4;
    const int m0 = blockIdx.y * 64, n0 = blockIdx.x * 64;
    const float* Wg[3] = {Wxr, Wxz, Wi};

    float4 acc[3][4];
#pragma unroll
    for (int g = 0; g < 3; ++g)
#pragma unroll
        for (int i = 0; i < 4; ++i) acc[g][i] = make_float4(0.f, 0.f, 0.f, 0.f);

    const int xrow = tid >> 2, xk = (tid & 3) * 4;
    const int wk = tid >> 4, wn = (tid & 15) * 4;

    for (int k0 = 0; k0 < EE; k0 += 16) {
        float4 xv = *(const float4*)(x + (size_t)(m0 + xrow) * EE + k0 + xk);
        xT[xk + 0][xrow] = xv.x;
        xT[xk + 1][xrow] = xv.y;
        xT[xk + 2][xrow] = xv.z;
        xT[xk + 3][xrow] = xv.w;
#pragma unroll
        for (int g = 0; g < 3; ++g) {
            float4 wv = *(const float4*)(Wg[g] + (size_t)(k0 + wk) * HH + n0 + wn);
            *(float4*)&wB[g][wk][wn] = wv;
        }
        __syncthreads();
#pragma unroll
        for (int kk = 0; kk < 16; ++kk) {
            float4 a  = *(const float4*)&xT[kk][ty * 4];
            float4 w0 = *(const float4*)&wB[0][kk][tx * 4];
            float4 w1 = *(const float4*)&wB[1][kk][tx * 4];
            float4 w2 = *(const float4*)&wB[2][kk][tx * 4];
            float as[4] = {a.x, a.y, a.z, a.w};
#pragma unroll
            for (int i = 0; i < 4; ++i) {
                FMA4(acc[0][i], as[i], w0);
                FMA4(acc[1][i], as[i], w1);
                FMA4(acc[2][i], as[i], w2);
            }
        }
        __syncthreads();
    }

    float4 bv0 = *(const float4*)(br + n0 + tx * 4);
    float4 bv1 = *(const float4*)(bz + n0 + tx * 4);
    float4 bv2 = *(const float4*)(bi + n0 + tx * 4);
#pragma unroll
    for (int i = 0; i < 4; ++i) {
        size_t m = (size_t)m0 + ty * 4 + i;
        size_t off = m * HH + n0 + tx * 4;
        float4 v0 = acc[0][i]; v0.x += bv0.x; v0.y += bv0.y; v0.z += bv0.z; v0.w += bv0.w;
        float4 v1 = acc[1][i]; v1.x += bv1.x; v1.y += bv1.y; v1.z += bv1.z; v1.w += bv1.w;
        float4 v2 = acc[2][i]; v2.x += bv2.x; v2.y += bv2.y; v2.z += bv2.z; v2.w += bv2.w;
        st_store(xr_out + off + 0, v0.x); st_store(xr_out + off + 1, v0.y);
        st_store(xr_out + off + 2, v0.z); st_store(xr_out + off + 3, v0.w);
        st_store(xz_out + off + 0, v1.x); st_store(xz_out + off + 1, v1.y);
        st_store(xz_out + off + 2, v1.z); st_store(xz_out + off + 3, v1.w);
        *(float4*)(xi_out + off) = v2;   // xi lives in d_out; overwritten with h later
    }
}

// =====================================================================
// DPP all-reduce over each row of 16 lanes (sum).
// =====================================================================
__device__ __forceinline__ float row16_allreduce(float v) {
    int y;
    y = __builtin_amdgcn_update_dpp(0, __float_as_int(v), 0xB1, 0xF, 0xF, true);  // quad_perm [1,0,3,2]
    v += __int_as_float(y);
    y = __builtin_amdgcn_update_dpp(0, __float_as_int(v), 0x4E, 0xF, 0xF, true);  // quad_perm [2,3,0,1]
    v += __int_as_float(y);
    y = __builtin_amdgcn_update_dpp(0, __float_as_int(v), 0x124, 0xF, 0xF, true); // row_ror:4
    v += __int_as_float(y);
    y = __builtin_amdgcn_update_dpp(0, __float_as_int(v), 0x128, 0xF, 0xF, true); // row_ror:8
    v += __int_as_float(y);
    return v;
}

// =====================================================================
// Fence-free two-level grid barrier. Relaxed agent-scope atomics only:
// no L2 writeback / invalidate (unlike cg::grid_group::sync). Correctness:
// all h traffic goes through LLC via sc1 (device-scope) accesses, and each
// block drains vmcnt(0) before signalling arrival.
// bar layout: bar[g*32] for g in [0,16) = group counters, bar[512] = root.
// Counters are monotonic; step1 is the 1-based barrier index.
// =====================================================================
__device__ __forceinline__ void xbar(u32* bar, int bid, unsigned step1) {
    __syncthreads();
    if (threadIdx.x == 0) {
        asm volatile("s_waitcnt vmcnt(0)" ::: "memory");   // h stores drained to LLC
        __builtin_amdgcn_sched_barrier(0);
        unsigned old = __hip_atomic_fetch_add(&bar[(bid >> 4) * 32], 1u,
                                              __ATOMIC_RELAXED, __HIP_MEMORY_SCOPE_AGENT);
        if (old == step1 * 16u - 1u)                        // last arrival in group
            __hip_atomic_fetch_add(&bar[512], 1u, __ATOMIC_RELAXED, __HIP_MEMORY_SCOPE_AGENT);
        while (__hip_atomic_load(&bar[512], __ATOMIC_RELAXED, __HIP_MEMORY_SCOPE_AGENT)
               < step1 * 16u) {
            __builtin_amdgcn_s_sleep(1);
        }
        __builtin_amdgcn_sched_barrier(0);
    }
    __syncthreads();
}

// =====================================================================
// Phase 2: persistent scan. 256 blocks x 256 threads, weights in registers.
// h ping-pongs through LLC (sc1 atomics); custom tree barrier per step.
// =====================================================================
template <typename ST>
__global__ __launch_bounds__(256, 1) void scan_kernel(
    const ST* __restrict__ xr, const ST* __restrict__ xz,
    const float* __restrict__ Whr, const float* __restrict__ Whz, const float* __restrict__ Wh,
    float* __restrict__ out,      // d_out: holds xi pre-activations, overwritten with h
    float* __restrict__ hbuf,     // [2][16][1024] fp32 (LLC-resident exchange buffer)
    u32* __restrict__ bar)
{
    __shared__ float4 hs[16 * 256];      // swizzled h (64 KB)
    __shared__ float red[4][4][48];      // [wave][cg][b*3+u]
    __shared__ float pre[12][16];        // [gate*4+c][b]

    const int tid = threadIdx.x, bid = blockIdx.x;
    const int lane = tid & 63, wv = tid >> 6;
    const int cgg = lane >> 4, kslo = lane & 15;
    const int ks = wv * 16 + kslo;       // 0..63, k in [16*ks, 16*ks+16)
    const int n0 = bid * 4;

    // ---- load recurrent weights into registers (one-time, plain loads) ----
    float4 wreg[3][4];
    {
        const float* WG[3] = {Whr, Whz, Wh};
#pragma unroll
        for (int u = 0; u < 3; ++u) {
            int ugc = cgg * 3 + u;           // 0..11 == gate*4 + c
            const float* W = WG[ugc >> 2];
            int col = n0 + (ugc & 3);
#pragma unroll
            for (int j = 0; j < 4; ++j) {
                int kb = ks * 16 + j * 4;
                wreg[u][j] = make_float4(W[(size_t)(kb + 0) * HH + col],
                                         W[(size_t)(kb + 1) * HH + col],
                                         W[(size_t)(kb + 2) * HH + col],
                                         W[(size_t)(kb + 3) * HH + col]);
            }
        }
    }

    // ---- zero h_0 (buffer 0) through LLC ----
    if (tid < 64)
        __hip_atomic_store(&hbuf[bid * 64 + tid], 0.f, __ATOMIC_RELAXED, __HIP_MEMORY_SCOPE_AGENT);
    unsigned bstep = 1;
    xbar(bar, bid, bstep++);

    for (int t = 0; t < TT; ++t) {
        const float4* hin = (const float4*)(hbuf + (size_t)(t & 1) * (BB * HH));
        float* hout = hbuf + (size_t)((t + 1) & 1) * (BB * HH);

        // ---- stage h: batch 32x8B LLC loads into regs, then LDS (swizzled) ----
        float4 tmp[16];
#pragma unroll
        for (int i = 0; i < 16; ++i) {
            const u64* p = (const u64*)(hin + tid + i * 256);
            u64 lo = __hip_atomic_load(p + 0, __ATOMIC_RELAXED, __HIP_MEMORY_SCOPE_AGENT);
            u64 hi = __hip_atomic_load(p + 1, __ATOMIC_RELAXED, __HIP_MEMORY_SCOPE_AGENT);
            ((u64*)&tmp[i])[0] = lo;
            ((u64*)&tmp[i])[1] = hi;
        }
#pragma unroll
        for (int i = 0; i < 16; ++i) {
            int q = tid + i * 256;           // b = q>>8, slot s = q&255
            int s = q & 255;
            hs[(q & ~255) | (s ^ ((s >> 3) & 7))] = tmp[i];
        }
        __syncthreads();

        // ---- partial dot products: 768 FMA/thread ----
        float pacc[16][3];
#pragma unroll
        for (int b = 0; b < 16; ++b)
#pragma unroll
            for (int u = 0; u < 3; ++u) pacc[b][u] = 0.f;

#pragma unroll
        for (int b = 0; b < 16; ++b) {
#pragma unroll
            for (int j = 0; j < 4; ++j) {
                int s = ks * 4 + j;
                float4 h4 = hs[(b << 8) | (s ^ ((s >> 3) & 7))];
#pragma unroll
                for (int u = 0; u < 3; ++u) {
                    pacc[b][u] = fmaf(h4.x, wreg[u][j].x, pacc[b][u]);
                    pacc[b][u] = fmaf(h4.y, wreg[u][j].y, pacc[b][u]);
                    pacc[b][u] = fmaf(h4.z, wreg[u][j].z, pacc[b][u]);
                    pacc[b][u] = fmaf(h4.w, wreg[u][j].w, pacc[b][u]);
                }
            }
        }

        // ---- reduce over the 16 k-sub-slices in each wave row ----
#pragma unroll
        for (int b = 0; b < 16; ++b)
#pragma unroll
            for (int u = 0; u < 3; ++u) pacc[b][u] = row16_allreduce(pacc[b][u]);

        if (kslo == 0) {
#pragma unroll
            for (int b = 0; b < 16; ++b)
#pragma unroll
                for (int u = 0; u < 3; ++u) red[wv][cgg][b * 3 + u] = pacc[b][u];
        }
        __syncthreads();

        // ---- combine the 4 waves -> gate pre-activations ----
        if (tid < 192) {
            int b = tid & 15, ugc = tid >> 4;      // ugc = gate*4 + c
            int cq = ugc / 3, u = ugc % 3;
            pre[ugc][b] = red[0][cq][b * 3 + u] + red[1][cq][b * 3 + u] +
                          red[2][cq][b * 3 + u] + red[3][cq][b * 3 + u];
        }
        __syncthreads();

        // ---- elementwise GRU update for this block's 4 columns ----
        if (tid < 64) {
            int c = tid & 3, b = tid >> 2;
            size_t idx = (size_t)(b * TT + t) * HH + n0 + c;
            float dr = pre[c][b], dz = pre[4 + c][b], dh = pre[8 + c][b];
            float r = 1.f / (1.f + expf(-(dr + st_load(xr + idx))));
            float z = 1.f / (1.f + expf(-(dz + st_load(xz + idx))));
            float cand = tanhf(fmaf(r, dh, out[idx]));            // out holds xi
            int sb = bid ^ ((bid >> 3) & 7);                      // swizzled slot of col group
            float4 h4 = hs[(b << 8) | sb];
            float hprev = (c == 0) ? h4.x : ((c == 1) ? h4.y : ((c == 2) ? h4.z : h4.w));
            float hnew = fmaf(z, hprev - cand, cand);             // z*h + (1-z)*cand
            out[idx] = hnew;                                      // plain: block-private
            __hip_atomic_store(&hout[b * HH + n0 + c], hnew,
                               __ATOMIC_RELAXED, __HIP_MEMORY_SCOPE_AGENT);
        }
        xbar(bar, bid, bstep++);
    }
}

__global__ void sentinel_kernel(float* out) {
    if (threadIdx.x == 0 && blockIdx.x == 0) out[0] = 12345.0f;  // ws too small marker
}

// =====================================================================
extern "C" void kernel_launch(void* const* d_in, const int* in_sizes, int n_in,
                              void* d_out, int out_size, void* d_ws, size_t ws_size,
                              hipStream_t stream) {
    const float* x   = (const float*)d_in[0];
    const float* Wxr = (const float*)d_in[1];
    const float* Whr = (const float*)d_in[2];
    const float* br  = (const float*)d_in[3];
    const float* Wxz = (const float*)d_in[4];
    const float* Whz = (const float*)d_in[5];
    const float* bz  = (const float*)d_in[6];
    const float* Wi  = (const float*)d_in[7];
    const float* Wh  = (const float*)d_in[8];
    const float* bb  = (const float*)d_in[9];
    float* out = (float*)d_out;

    const size_t BTH = (size_t)BB * TT * HH;
    const size_t HBUF_ELTS = (size_t)2 * BB * HH;
    const size_t BAR_BYTES = 4096;
    const size_t need_f32 = 2 * BTH * sizeof(float) + HBUF_ELTS * sizeof(float) + BAR_BYTES;
    const size_t need_b16 = 2 * BTH * sizeof(__hip_bfloat16) + HBUF_ELTS * sizeof(float) + BAR_BYTES;

    dim3 pgrid(HH / 64, (BB * TT) / 64);   // (16, 256)

    if (ws_size >= need_f32) {
        float* xr = (float*)d_ws;
        float* xz = xr + BTH;
        float* hb = xz + BTH;
        u32* bar = (u32*)(hb + HBUF_ELTS);
        proj_kernel<float><<<pgrid, 256, 0, stream>>>(x, Wxr, br, Wxz, bz, Wi, bb, xr, xz, out, bar);
        const float* xrc = xr; const float* xzc = xz;
        void* args[8] = {(void*)&xrc, (void*)&xzc, (void*)&Whr, (void*)&Whz,
                         (void*)&Wh, (void*)&out, (void*)&hb, (void*)&bar};
        hipLaunchCooperativeKernel((void*)scan_kernel<float>, dim3(256), dim3(256),
                                   args, 0, stream);
    } else if (ws_size >= need_b16) {
        __hip_bfloat16* xr = (__hip_bfloat16*)d_ws;
        __hip_bfloat16* xz = xr + BTH;
        float* hb = (float*)(xz + BTH);
        u32* bar = (u32*)(hb + HBUF_ELTS);
        proj_kernel<__hip_bfloat16><<<pgrid, 256, 0, stream>>>(x, Wxr, br, Wxz, bz, Wi, bb, xr, xz, out, bar);
        const __hip_bfloat16* xrc = xr; const __hip_bfloat16* xzc = xz;
        void* args[8] = {(void*)&xrc, (void*)&xzc, (void*)&Whr, (void*)&Whz,
                         (void*)&Wh, (void*)&out, (void*)&hb, (void*)&bar};
        hipLaunchCooperativeKernel((void*)scan_kernel<__hip_bfloat16>, dim3(256), dim3(256),
                                   args, 0, stream);
    } else {
        sentinel_kernel<<<1, 64, 0, stream>>>(out);   // diagnosable failure mode
    }
}

// Round 3
// 9055.325 us; speedup vs baseline: 4.2339x; 1.1779x over previous
//
#include <hip/hip_runtime.h>
#include <hip/hip_bf16.h>
#include <cstddef>
#include <cstdint>

static constexpr int BB = 16;    // batch
static constexpr int TT = 1024;  // time steps
static constexpr int EE = 512;   // input dim
static constexpr int HH = 1024;  // hidden dim

using u32 = unsigned int;
using u64 = unsigned long long;
typedef float f32x4 __attribute__((ext_vector_type(4)));

// ---------- storage-type helpers (fp32 or bf16 scratch for xr/xz) ----------
__device__ __forceinline__ float st_load(const float* p) { return *p; }
__device__ __forceinline__ float st_load(const __hip_bfloat16* p) { return __bfloat162float(*p); }
__device__ __forceinline__ void st_store(float* p, float v) { *p = v; }
__device__ __forceinline__ void st_store(__hip_bfloat16* p, float v) { *p = __float2bfloat16(v); }

// 16B device-scope (L2-bypassing, LLC-coherent) load. No waitcnt here —
// batch-issue then drain once with llc_drain().
__device__ __forceinline__ void llc_load(f32x4& d, const f32x4* p) {
    asm volatile("global_load_dwordx4 %0, %1, off sc0 sc1" : "=v"(d) : "v"(p));
}
__device__ __forceinline__ void llc_drain() {
    asm volatile("s_waitcnt vmcnt(0)" ::: "memory");
    __builtin_amdgcn_sched_barrier(0);
}

#define FMA4(ACC, S, W)                         \
    (ACC).x = fmaf((S), (W).x, (ACC).x);        \
    (ACC).y = fmaf((S), (W).y, (ACC).y);        \
    (ACC).z = fmaf((S), (W).z, (ACC).z);        \
    (ACC).w = fmaf((S), (W).w, (ACC).w);

// =====================================================================
// Phase 1: xr = x@Wxr+br -> ws, xz = x@Wxz+bz -> ws, xi = x@Wi+b -> d_out
// Also zeroes the scan kernel's barrier counters (block 0).
// =====================================================================
template <typename ST>
__global__ __launch_bounds__(256) void proj_kernel(
    const float* __restrict__ x,
    const float* __restrict__ Wxr, const float* __restrict__ br,
    const float* __restrict__ Wxz, const float* __restrict__ bz,
    const float* __restrict__ Wi,  const float* __restrict__ bi,
    ST* __restrict__ xr_out, ST* __restrict__ xz_out, float* __restrict__ xi_out,
    u32* __restrict__ bar)
{
    __shared__ float xT[16][68];
    __shared__ float wB[3][16][64];

    const int tid = threadIdx.x;
    if (blockIdx.x == 0 && blockIdx.y == 0 && tid < 17) bar[tid * 32] = 0u;

    const int tx = tid & 15, ty = tid >> 4;
    const int m0 = blockIdx.y * 64, n0 = blockIdx.x * 64;
    const float* Wg[3] = {Wxr, Wxz, Wi};

    float4 acc[3][4];
#pragma unroll
    for (int g = 0; g < 3; ++g)
#pragma unroll
        for (int i = 0; i < 4; ++i) acc[g][i] = make_float4(0.f, 0.f, 0.f, 0.f);

    const int xrow = tid >> 2, xk = (tid & 3) * 4;
    const int wk = tid >> 4, wn = (tid & 15) * 4;

    for (int k0 = 0; k0 < EE; k0 += 16) {
        float4 xv = *(const float4*)(x + (size_t)(m0 + xrow) * EE + k0 + xk);
        xT[xk + 0][xrow] = xv.x;
        xT[xk + 1][xrow] = xv.y;
        xT[xk + 2][xrow] = xv.z;
        xT[xk + 3][xrow] = xv.w;
#pragma unroll
        for (int g = 0; g < 3; ++g) {
            float4 wv = *(const float4*)(Wg[g] + (size_t)(k0 + wk) * HH + n0 + wn);
            *(float4*)&wB[g][wk][wn] = wv;
        }
        __syncthreads();
#pragma unroll
        for (int kk = 0; kk < 16; ++kk) {
            float4 a  = *(const float4*)&xT[kk][ty * 4];
            float4 w0 = *(const float4*)&wB[0][kk][tx * 4];
            float4 w1 = *(const float4*)&wB[1][kk][tx * 4];
            float4 w2 = *(const float4*)&wB[2][kk][tx * 4];
            float as[4] = {a.x, a.y, a.z, a.w};
#pragma unroll
            for (int i = 0; i < 4; ++i) {
                FMA4(acc[0][i], as[i], w0);
                FMA4(acc[1][i], as[i], w1);
                FMA4(acc[2][i], as[i], w2);
            }
        }
        __syncthreads();
    }

    float4 bv0 = *(const float4*)(br + n0 + tx * 4);
    float4 bv1 = *(const float4*)(bz + n0 + tx * 4);
    float4 bv2 = *(const float4*)(bi + n0 + tx * 4);
#pragma unroll
    for (int i = 0; i < 4; ++i) {
        size_t m = (size_t)m0 + ty * 4 + i;
        size_t off = m * HH + n0 + tx * 4;
        float4 v0 = acc[0][i]; v0.x += bv0.x; v0.y += bv0.y; v0.z += bv0.z; v0.w += bv0.w;
        float4 v1 = acc[1][i]; v1.x += bv1.x; v1.y += bv1.y; v1.z += bv1.z; v1.w += bv1.w;
        float4 v2 = acc[2][i]; v2.x += bv2.x; v2.y += bv2.y; v2.z += bv2.z; v2.w += bv2.w;
        st_store(xr_out + off + 0, v0.x); st_store(xr_out + off + 1, v0.y);
        st_store(xr_out + off + 2, v0.z); st_store(xr_out + off + 3, v0.w);
        st_store(xz_out + off + 0, v1.x); st_store(xz_out + off + 1, v1.y);
        st_store(xz_out + off + 2, v1.z); st_store(xz_out + off + 3, v1.w);
        *(float4*)(xi_out + off) = v2;
    }
}

// =====================================================================
// DPP all-reduce over each row of 16 lanes (sum).
// =====================================================================
__device__ __forceinline__ float row16_allreduce(float v) {
    int y;
    y = __builtin_amdgcn_update_dpp(0, __float_as_int(v), 0xB1, 0xF, 0xF, true);  // quad_perm [1,0,3,2]
    v += __int_as_float(y);
    y = __builtin_amdgcn_update_dpp(0, __float_as_int(v), 0x4E, 0xF, 0xF, true);  // quad_perm [2,3,0,1]
    v += __int_as_float(y);
    y = __builtin_amdgcn_update_dpp(0, __float_as_int(v), 0x124, 0xF, 0xF, true); // row_ror:4
    v += __int_as_float(y);
    y = __builtin_amdgcn_update_dpp(0, __float_as_int(v), 0x128, 0xF, 0xF, true); // row_ror:8
    v += __int_as_float(y);
    return v;
}

// =====================================================================
// Fence-free two-level grid barrier (relaxed agent-scope atomics).
// bar[g*32], g<16 = group counters; bar[512] = root. Monotonic counters.
// =====================================================================
__device__ __forceinline__ void xbar(u32* bar, int bid, unsigned step1) {
    __syncthreads();   // also drains each thread's vmem (compiler waitcnt)
    if (threadIdx.x == 0) {
        asm volatile("s_waitcnt vmcnt(0)" ::: "memory");
        __builtin_amdgcn_sched_barrier(0);
        unsigned old = __hip_atomic_fetch_add(&bar[(bid >> 4) * 32], 1u,
                                              __ATOMIC_RELAXED, __HIP_MEMORY_SCOPE_AGENT);
        if (old == step1 * 16u - 1u)
            __hip_atomic_fetch_add(&bar[512], 1u, __ATOMIC_RELAXED, __HIP_MEMORY_SCOPE_AGENT);
        while (__hip_atomic_load(&bar[512], __ATOMIC_RELAXED, __HIP_MEMORY_SCOPE_AGENT)
               < step1 * 16u) {
            __builtin_amdgcn_s_sleep(1);
        }
        __builtin_amdgcn_sched_barrier(0);
    }
    __syncthreads();
}

// =====================================================================
// Phase 2: persistent scan. 256 blocks x 512 threads (8 waves, 2/SIMD).
// Block owns 4 hidden cols x 3 gates. Weights in registers (24 f32/thread).
// h ping-pongs through LLC via 16B sc0/sc1 loads; custom barrier per step.
// Thread (wv, cgg, kslo): units u=cgg*3+u, k-slice [8*ks, 8*ks+8),
// ks = wv*16+kslo in [0,128).
// =====================================================================
template <typename ST>
__global__ __launch_bounds__(512, 1) void scan_kernel(
    const ST* __restrict__ xr, const ST* __restrict__ xz,
    const float* __restrict__ Whr, const float* __restrict__ Whz, const float* __restrict__ Wh,
    float* __restrict__ out,      // d_out: holds xi pre-activations, overwritten with h
    float* __restrict__ hbuf,     // [2][16][1024] fp32 (LLC-resident exchange)
    u32* __restrict__ bar)
{
    __shared__ f32x4 hs[16 * 256];       // 64 KB, slot-swizzled s^((s>>3)&1)
    __shared__ float red[8][4][48];      // [wave][cgg][b*3+u]
    __shared__ float pre[12][16];        // [gate*4+c][b]

    const int tid = threadIdx.x, bid = blockIdx.x;
    const int lane = tid & 63, wv = tid >> 6;      // wv 0..7
    const int cgg = lane >> 4, kslo = lane & 15;
    const int ks = wv * 16 + kslo;                  // 0..127
    const int n0 = bid * 4;

    // ---- recurrent weights -> registers (one-time) ----
    float wreg[3][8];
    {
        const float* WG[3] = {Whr, Whz, Wh};
#pragma unroll
        for (int u = 0; u < 3; ++u) {
            int ugc = cgg * 3 + u;                  // 0..11 == gate*4 + c
            const float* W = WG[ugc >> 2];
            int col = n0 + (ugc & 3);
#pragma unroll
            for (int j = 0; j < 8; ++j)
                wreg[u][j] = W[(size_t)(ks * 8 + j) * HH + col];
        }
    }

    if (tid < 64)
        __hip_atomic_store(&hbuf[bid * 64 + tid], 0.f, __ATOMIC_RELAXED, __HIP_MEMORY_SCOPE_AGENT);

    // ---- prologue prefetch for t=0 ----
    float pxr = 0.f, pxz = 0.f, pxi = 0.f;
    const int tc = tid & 3, tb = tid >> 2;          // tail mapping (tid<64)
    if (tid < 64) {
        size_t idx = (size_t)(tb * TT + 0) * HH + n0 + tc;
        pxr = st_load(xr + idx); pxz = st_load(xz + idx); pxi = out[idx];
    }

    unsigned bstep = 1;
    xbar(bar, bid, bstep++);

    const int sw = (ks >> 2) & 1;                   // sigma flip bit for this thread's pair

    for (int t = 0; t < TT; ++t) {
        const f32x4* hin = (const f32x4*)(hbuf + (size_t)(t & 1) * (BB * HH));
        float* hout = hbuf + (size_t)((t + 1) & 1) * (BB * HH);

        // ---- broadcast staging: 8 x 16B sc1 loads, staggered by bid ----
        f32x4 tmp[8];
#pragma unroll
        for (int i = 0; i < 8; ++i) {
            int q = (tid + i * 512 + (bid << 4)) & 4095;
            llc_load(tmp[i], hin + q);
        }
        llc_drain();
#pragma unroll
        for (int i = 0; i < 8; ++i) {
            int q = (tid + i * 512 + (bid << 4)) & 4095;
            int s = q & 255;
            hs[(q & ~255) | (s ^ ((s >> 3) & 1))] = tmp[i];
        }
        __syncthreads();

        // ---- partial dots: 384 FMA/thread ----
        float pacc[16][3];
#pragma unroll
        for (int b = 0; b < 16; ++b)
#pragma unroll
            for (int u = 0; u < 3; ++u) pacc[b][u] = 0.f;

#pragma unroll
        for (int b = 0; b < 16; ++b) {
            f32x4 ha = hs[(b << 8) | ((2 * ks) ^ sw)];
            f32x4 hb = hs[(b << 8) | ((2 * ks + 1) ^ sw)];
#pragma unroll
            for (int u = 0; u < 3; ++u) {
                float a = pacc[b][u];
                a = fmaf(ha[0], wreg[u][0], a);
                a = fmaf(ha[1], wreg[u][1], a);
                a = fmaf(ha[2], wreg[u][2], a);
                a = fmaf(ha[3], wreg[u][3], a);
                a = fmaf(hb[0], wreg[u][4], a);
                a = fmaf(hb[1], wreg[u][5], a);
                a = fmaf(hb[2], wreg[u][6], a);
                a = fmaf(hb[3], wreg[u][7], a);
                pacc[b][u] = a;
            }
        }

        // ---- reduce over kslo (16 lanes per row) ----
#pragma unroll
        for (int b = 0; b < 16; ++b)
#pragma unroll
            for (int u = 0; u < 3; ++u) pacc[b][u] = row16_allreduce(pacc[b][u]);

        if (kslo == 0) {
#pragma unroll
            for (int b = 0; b < 16; ++b)
#pragma unroll
                for (int u = 0; u < 3; ++u) red[wv][cgg][b * 3 + u] = pacc[b][u];
        }
        __syncthreads();

        // ---- combine 8 waves -> gate pre-activations ----
        if (tid < 192) {
            int b = tid & 15, ugc = tid >> 4;
            int cq = ugc / 3, u = ugc % 3;
            float s = 0.f;
#pragma unroll
            for (int w = 0; w < 8; ++w) s += red[w][cq][b * 3 + u];
            pre[ugc][b] = s;
        }
        __syncthreads();

        // ---- elementwise GRU update (prefetched operands) ----
        if (tid < 64) {
            size_t idx = (size_t)(tb * TT + t) * HH + n0 + tc;
            float dr = pre[tc][tb], dz = pre[4 + tc][tb], dh = pre[8 + tc][tb];
            float r = 1.f / (1.f + expf(-(dr + pxr)));
            float z = 1.f / (1.f + expf(-(dz + pxz)));
            float cand = tanhf(fmaf(r, dh, pxi));
            int sb = bid ^ ((bid >> 3) & 1);                  // sigma(bid)
            f32x4 h4 = hs[(tb << 8) | sb];
            float hprev = (tc == 0) ? h4[0] : ((tc == 1) ? h4[1] : ((tc == 2) ? h4[2] : h4[3]));
            float hnew = fmaf(z, hprev - cand, cand);         // z*h + (1-z)*cand
            out[idx] = hnew;
            __hip_atomic_store(&hout[tb * HH + n0 + tc], hnew,
                               __ATOMIC_RELAXED, __HIP_MEMORY_SCOPE_AGENT);
            // ---- prefetch t+1 (hidden under barrier) ----
            if (t + 1 < TT) {
                size_t idx2 = idx + HH;
                pxr = st_load(xr + idx2); pxz = st_load(xz + idx2); pxi = out[idx2];
            }
        }
        xbar(bar, bid, bstep++);
    }
}

__global__ void sentinel_kernel(float* out) {
    if (threadIdx.x == 0 && blockIdx.x == 0) out[0] = 12345.0f;
}

// =====================================================================
extern "C" void kernel_launch(void* const* d_in, const int* in_sizes, int n_in,
                              void* d_out, int out_size, void* d_ws, size_t ws_size,
                              hipStream_t stream) {
    const float* x   = (const float*)d_in[0];
    const float* Wxr = (const float*)d_in[1];
    const float* Whr = (const float*)d_in[2];
    const float* br  = (const float*)d_in[3];
    const float* Wxz = (const float*)d_in[4];
    const float* Whz = (const float*)d_in[5];
    const float* bz  = (const float*)d_in[6];
    const float* Wi  = (const float*)d_in[7];
    const float* Wh  = (const float*)d_in[8];
    const float* bb  = (const float*)d_in[9];
    float* out = (float*)d_out;

    const size_t BTH = (size_t)BB * TT * HH;
    const size_t HBUF_ELTS = (size_t)2 * BB * HH;
    const size_t BAR_BYTES = 4096;
    const size_t need_f32 = 2 * BTH * sizeof(float) + HBUF_ELTS * sizeof(float) + BAR_BYTES;
    const size_t need_b16 = 2 * BTH * sizeof(__hip_bfloat16) + HBUF_ELTS * sizeof(float) + BAR_BYTES;

    dim3 pgrid(HH / 64, (BB * TT) / 64);   // (16, 256)

    if (ws_size >= need_f32) {
        float* xr = (float*)d_ws;
        float* xz = xr + BTH;
        float* hb = xz + BTH;
        u32* bar = (u32*)(hb + HBUF_ELTS);
        proj_kernel<float><<<pgrid, 256, 0, stream>>>(x, Wxr, br, Wxz, bz, Wi, bb, xr, xz, out, bar);
        const float* xrc = xr; const float* xzc = xz;
        void* args[8] = {(void*)&xrc, (void*)&xzc, (void*)&Whr, (void*)&Whz,
                         (void*)&Wh, (void*)&out, (void*)&hb, (void*)&bar};
        hipLaunchCooperativeKernel((void*)scan_kernel<float>, dim3(256), dim3(512),
                                   args, 0, stream);
    } else if (ws_size >= need_b16) {
        __hip_bfloat16* xr = (__hip_bfloat16*)d_ws;
        __hip_bfloat16* xz = xr + BTH;
        float* hb = (float*)(xz + BTH);
        u32* bar = (u32*)(hb + HBUF_ELTS);
        proj_kernel<__hip_bfloat16><<<pgrid, 256, 0, stream>>>(x, Wxr, br, Wxz, bz, Wi, bb, xr, xz, out, bar);
        const __hip_bfloat16* xrc = xr; const __hip_bfloat16* xzc = xz;
        void* args[8] = {(void*)&xrc, (void*)&xzc, (void*)&Whr, (void*)&Whz,
                         (void*)&Wh, (void*)&out, (void*)&hb, (void*)&bar};
        hipLaunchCooperativeKernel((void*)scan_kernel<__hip_bfloat16>, dim3(256), dim3(512),
                                   args, 0, stream);
    } else {
        sentinel_kernel<<<1, 64, 0, stream>>>(out);
    }
}

// Round 4
// 5703.352 us; speedup vs baseline: 6.7222x; 1.5877x over previous
//
#include <hip/hip_runtime.h>
#include <hip/hip_bf16.h>
#include <cstddef>
#include <cstdint>

static constexpr int BB = 16;    // batch
static constexpr int TT = 1024;  // time steps
static constexpr int EE = 512;   // input dim
static constexpr int HH = 1024;  // hidden dim

// scan decomposition: 4 groups x 64 blocks; group owns 4 batches, all cols.
static constexpr int NG   = 4;    // batch groups
static constexpr int GBLK = 64;   // blocks per group
static constexpr int BPG  = 4;    // batches per group
static constexpr int COLS = 16;   // hidden columns per block

using u32 = unsigned int;
using u64 = unsigned long long;
typedef float f32x4 __attribute__((ext_vector_type(4)));

// ---------- storage-type helpers (fp32 or bf16 scratch for xr/xz) ----------
__device__ __forceinline__ float st_load(const float* p) { return *p; }
__device__ __forceinline__ float st_load(const __hip_bfloat16* p) { return __bfloat162float(*p); }
__device__ __forceinline__ void st_store(float* p, float v) { *p = v; }
__device__ __forceinline__ void st_store(__hip_bfloat16* p, float v) { *p = __float2bfloat16(v); }

// 16B device-scope (L1/L2-bypassing, LLC-coherent) load. Batch-issue, then
// drain once with llc_drain() — inline-asm loads are NOT compiler-tracked.
__device__ __forceinline__ void llc_load(f32x4& d, const f32x4* p) {
    asm volatile("global_load_dwordx4 %0, %1, off sc0 sc1" : "=v"(d) : "v"(p));
}
__device__ __forceinline__ void llc_drain() {
    asm volatile("s_waitcnt vmcnt(0)" ::: "memory");
    __builtin_amdgcn_sched_barrier(0);
}

#define FMA4(ACC, S, W)                         \
    (ACC).x = fmaf((S), (W).x, (ACC).x);        \
    (ACC).y = fmaf((S), (W).y, (ACC).y);        \
    (ACC).z = fmaf((S), (W).z, (ACC).z);        \
    (ACC).w = fmaf((S), (W).w, (ACC).w);

// =====================================================================
// Phase 1: xr = x@Wxr+br -> ws, xz = x@Wxz+bz -> ws, xi = x@Wi+b -> d_out
// Also zeroes the scan kernel's barrier counters (block (0,0)).
// =====================================================================
template <typename ST>
__global__ __launch_bounds__(256) void proj_kernel(
    const float* __restrict__ x,
    const float* __restrict__ Wxr, const float* __restrict__ br,
    const float* __restrict__ Wxz, const float* __restrict__ bz,
    const float* __restrict__ Wi,  const float* __restrict__ bi,
    ST* __restrict__ xr_out, ST* __restrict__ xz_out, float* __restrict__ xi_out,
    u32* __restrict__ bar)
{
    __shared__ float xT[16][68];
    __shared__ float wB[3][16][64];

    const int tid = threadIdx.x;
    if (blockIdx.x == 0 && blockIdx.y == 0) bar[tid] = 0u;   // 1KB of counters

    const int tx = tid & 15, ty = tid >> 4;
    const int m0 = blockIdx.y * 64, n0 = blockIdx.x * 64;
    const float* Wg[3] = {Wxr, Wxz, Wi};

    float4 acc[3][4];
#pragma unroll
    for (int g = 0; g < 3; ++g)
#pragma unroll
        for (int i = 0; i < 4; ++i) acc[g][i] = make_float4(0.f, 0.f, 0.f, 0.f);

    const int xrow = tid >> 2, xk = (tid & 3) * 4;
    const int wk = tid >> 4, wn = (tid & 15) * 4;

    for (int k0 = 0; k0 < EE; k0 += 16) {
        float4 xv = *(const float4*)(x + (size_t)(m0 + xrow) * EE + k0 + xk);
        xT[xk + 0][xrow] = xv.x;
        xT[xk + 1][xrow] = xv.y;
        xT[xk + 2][xrow] = xv.z;
        xT[xk + 3][xrow] = xv.w;
#pragma unroll
        for (int g = 0; g < 3; ++g) {
            float4 wv = *(const float4*)(Wg[g] + (size_t)(k0 + wk) * HH + n0 + wn);
            *(float4*)&wB[g][wk][wn] = wv;
        }
        __syncthreads();
#pragma unroll
        for (int kk = 0; kk < 16; ++kk) {
            float4 a  = *(const float4*)&xT[kk][ty * 4];
            float4 w0 = *(const float4*)&wB[0][kk][tx * 4];
            float4 w1 = *(const float4*)&wB[1][kk][tx * 4];
            float4 w2 = *(const float4*)&wB[2][kk][tx * 4];
            float as[4] = {a.x, a.y, a.z, a.w};
#pragma unroll
            for (int i = 0; i < 4; ++i) {
                FMA4(acc[0][i], as[i], w0);
                FMA4(acc[1][i], as[i], w1);
                FMA4(acc[2][i], as[i], w2);
            }
        }
        __syncthreads();
    }

    float4 bv0 = *(const float4*)(br + n0 + tx * 4);
    float4 bv1 = *(const float4*)(bz + n0 + tx * 4);
    float4 bv2 = *(const float4*)(bi + n0 + tx * 4);
#pragma unroll
    for (int i = 0; i < 4; ++i) {
        size_t m = (size_t)m0 + ty * 4 + i;
        size_t off = m * HH + n0 + tx * 4;
        float4 v0 = acc[0][i]; v0.x += bv0.x; v0.y += bv0.y; v0.z += bv0.z; v0.w += bv0.w;
        float4 v1 = acc[1][i]; v1.x += bv1.x; v1.y += bv1.y; v1.z += bv1.z; v1.w += bv1.w;
        float4 v2 = acc[2][i]; v2.x += bv2.x; v2.y += bv2.y; v2.z += bv2.z; v2.w += bv2.w;
        st_store(xr_out + off + 0, v0.x); st_store(xr_out + off + 1, v0.y);
        st_store(xr_out + off + 2, v0.z); st_store(xr_out + off + 3, v0.w);
        st_store(xz_out + off + 0, v1.x); st_store(xz_out + off + 1, v1.y);
        st_store(xz_out + off + 2, v1.z); st_store(xz_out + off + 3, v1.w);
        *(float4*)(xi_out + off) = v2;
    }
}

// =====================================================================
// DPP all-reduce over each row of 16 lanes (sum).
// =====================================================================
__device__ __forceinline__ float row16_allreduce(float v) {
    int y;
    y = __builtin_amdgcn_update_dpp(0, __float_as_int(v), 0xB1, 0xF, 0xF, true);  // quad_perm [1,0,3,2]
    v += __int_as_float(y);
    y = __builtin_amdgcn_update_dpp(0, __float_as_int(v), 0x4E, 0xF, 0xF, true);  // quad_perm [2,3,0,1]
    v += __int_as_float(y);
    y = __builtin_amdgcn_update_dpp(0, __float_as_int(v), 0x124, 0xF, 0xF, true); // row_ror:4
    v += __int_as_float(y);
    y = __builtin_amdgcn_update_dpp(0, __float_as_int(v), 0x128, 0xF, 0xF, true); // row_ror:8
    v += __int_as_float(y);
    return v;
}

// =====================================================================
// Flat per-group barrier (relaxed agent-scope atomics, no cache fences).
// ctr = this group's counter (own 256B-separated line). Monotonic.
// Caller guarantees all prior device-visible stores were issued by wave 0
// (tid<64) — tid 0's vmcnt(0) drains them before the arrival add.
// =====================================================================
__device__ __forceinline__ void xbar(u32* ctr, unsigned target) {
    __syncthreads();
    if (threadIdx.x == 0) {
        asm volatile("s_waitcnt vmcnt(0)" ::: "memory");
        __builtin_amdgcn_sched_barrier(0);
        __hip_atomic_fetch_add(ctr, 1u, __ATOMIC_RELAXED, __HIP_MEMORY_SCOPE_AGENT);
        while (__hip_atomic_load(ctr, __ATOMIC_RELAXED, __HIP_MEMORY_SCOPE_AGENT) < target) {
            __builtin_amdgcn_s_sleep(1);
        }
        __builtin_amdgcn_sched_barrier(0);
    }
    __syncthreads();
}

// =====================================================================
// Phase 2: persistent scan, batch-split. 4 groups x 64 blocks x 512 thr.
// Group g owns batches [4g,4g+4); block (gb) owns cols [16gb,16gb+16) x 3
// gates, weights in registers (96 f32/thread). h exchange: 16KB per block
// per step through LLC; flat 64-arrival barrier per group.
// Thread (wv,cgg,kslo): ks=wv*16+kslo -> k-slice [8ks,8ks+8); cgg owns 12
// gate-col units ugc=cgg*12+u (gate=ugc>>4, col=ugc&15).
// =====================================================================
template <typename ST>
__global__ __launch_bounds__(512, 1) void scan_kernel(
    const ST* __restrict__ xr, const ST* __restrict__ xz,
    const float* __restrict__ Whr, const float* __restrict__ Whz, const float* __restrict__ Wh,
    float* __restrict__ out,      // d_out: holds xi pre-activations, overwritten with h
    float* __restrict__ hbuf,     // [2][16][1024] fp32 (LLC-resident exchange)
    u32* __restrict__ bar)
{
    __shared__ f32x4 hs[BPG * 256];      // 16KB: group's h, slot-swizzled
    __shared__ float red[8][4][48];      // [wave][cgg][b4*12+u]
    __shared__ float pre[48][4];         // [gate*16+col][b4]

    const int tid = threadIdx.x, bid = blockIdx.x;
    const int lane = tid & 63, wv = tid >> 6;       // wv 0..7
    const int cgg = lane >> 4, kslo = lane & 15;
    const int ks = wv * 16 + kslo;                  // 0..127
    const int group = bid >> 6, gb = bid & 63;
    const int n0 = gb * COLS;                       // global column base
    u32* ctr = bar + group * 64;                    // 256B-separated lines

    // ---- recurrent weights -> registers (one-time): 12 units x 8 k ----
    float wreg[12][8];
    {
        const float* WG[3] = {Whr, Whz, Wh};
#pragma unroll
        for (int u = 0; u < 12; ++u) {
            int ugc = cgg * 12 + u;                 // 0..47
            const float* W = WG[ugc >> 4];
            int col = n0 + (ugc & 15);
#pragma unroll
            for (int j = 0; j < 8; ++j)
                wreg[u][j] = W[(size_t)(ks * 8 + j) * HH + col];
        }
    }

    // ---- zero h_0 (buffer 0); block bid covers [bid*64, bid*64+64) which
    // lies inside its own group's batch rows, so the group barrier suffices.
    if (tid < 64)
        __hip_atomic_store(&hbuf[bid * 64 + tid], 0.f, __ATOMIC_RELAXED, __HIP_MEMORY_SCOPE_AGENT);

    // ---- prologue prefetch for t=0 (tail threads) ----
    float pxr = 0.f, pxz = 0.f, pxi = 0.f;
    const int tb4 = tid >> 4, tc = tid & 15;        // tail mapping (tid<64)
    const int tbg = group * BPG + tb4;              // global batch
    if (tid < 64) {
        size_t idx = (size_t)(tbg * TT + 0) * HH + n0 + tc;
        pxr = st_load(xr + idx); pxz = st_load(xz + idx); pxi = out[idx];
    }

    unsigned bstep = 1;
    xbar(ctr, bstep * GBLK); ++bstep;

    for (int t = 0; t < TT; ++t) {
        const f32x4* hin = (const f32x4*)(hbuf + (size_t)(t & 1) * (BB * HH) + group * BPG * HH);
        float* hout = hbuf + (size_t)((t + 1) & 1) * (BB * HH) + group * BPG * HH;

        // ---- broadcast staging: 2 x 16B LLC loads/thread, bid-staggered ----
        f32x4 tmp0, tmp1;
        int q0 = (tid + (gb << 3)) & 1023;
        int q1 = (tid + 512 + (gb << 3)) & 1023;
        llc_load(tmp0, hin + q0);
        llc_load(tmp1, hin + q1);
        llc_drain();
        {
            int s0 = q0 & 255, s1 = q1 & 255;
            hs[(q0 & 0x300) | (s0 ^ ((s0 >> 3) & 7))] = tmp0;
            hs[(q1 & 0x300) | (s1 ^ ((s1 >> 3) & 7))] = tmp1;
        }
        __syncthreads();

        // ---- partial dots: 4 batches x 12 units x 8 k = 384 FMA/thread ----
        float pacc[4][12];
#pragma unroll
        for (int b = 0; b < 4; ++b)
#pragma unroll
            for (int u = 0; u < 12; ++u) pacc[b][u] = 0.f;

        const int s0 = 2 * ks;                       // even slot of this k-slice
        const int c0 = (s0 >> 3) & 7;                // shared swizzle bits
        const int sl0 = s0 ^ c0;                     // swizzled even slot
#pragma unroll
        for (int b = 0; b < 4; ++b) {
            f32x4 ha = hs[(b << 8) | sl0];
            f32x4 hb = hs[(b << 8) | (sl0 ^ 1)];     // odd slot = even ^ 1
#pragma unroll
            for (int u = 0; u < 12; ++u) {
                float a = pacc[b][u];
                a = fmaf(ha[0], wreg[u][0], a);
                a = fmaf(ha[1], wreg[u][1], a);
                a = fmaf(ha[2], wreg[u][2], a);
                a = fmaf(ha[3], wreg[u][3], a);
                a = fmaf(hb[0], wreg[u][4], a);
                a = fmaf(hb[1], wreg[u][5], a);
                a = fmaf(hb[2], wreg[u][6], a);
                a = fmaf(hb[3], wreg[u][7], a);
                pacc[b][u] = a;
            }
        }

        // ---- reduce over kslo (16 lanes per row) ----
#pragma unroll
        for (int b = 0; b < 4; ++b)
#pragma unroll
            for (int u = 0; u < 12; ++u) pacc[b][u] = row16_allreduce(pacc[b][u]);

        if (kslo == 0) {
#pragma unroll
            for (int b = 0; b < 4; ++b)
#pragma unroll
                for (int u = 0; u < 12; ++u) red[wv][cgg][b * 12 + u] = pacc[b][u];
        }
        __syncthreads();

        // ---- combine 8 waves -> 192 gate pre-activations ----
        if (tid < 192) {
            int b4 = tid & 3, ugc = tid >> 2;        // ugc in [0,48)
            int cq = ugc / 12, u = ugc - cq * 12;
            float s = 0.f;
#pragma unroll
            for (int w = 0; w < 8; ++w) s += red[w][cq][b4 * 12 + u];
            pre[ugc][b4] = s;
        }
        __syncthreads();

        // ---- elementwise GRU update for this block's 16 cols x 4 batches ----
        if (tid < 64) {
            size_t idx = (size_t)(tbg * TT + t) * HH + n0 + tc;
            float dr = pre[tc][tb4], dz = pre[16 + tc][tb4], dh = pre[32 + tc][tb4];
            float r = 1.f / (1.f + expf(-(dr + pxr)));
            float z = 1.f / (1.f + expf(-(dz + pxz)));
            float cand = tanhf(fmaf(r, dh, pxi));
            int colg = n0 + tc;
            int sp = colg >> 2;
            f32x4 h4 = hs[(tb4 << 8) | (sp ^ ((sp >> 3) & 7))];
            int cc = colg & 3;
            float hprev = (cc == 0) ? h4[0] : ((cc == 1) ? h4[1] : ((cc == 2) ? h4[2] : h4[3]));
            float hnew = fmaf(z, hprev - cand, cand);         // z*h + (1-z)*cand
            out[idx] = hnew;
            __hip_atomic_store(&hout[tb4 * HH + colg], hnew,
                               __ATOMIC_RELAXED, __HIP_MEMORY_SCOPE_AGENT);
            // ---- prefetch t+1 operands (hidden under the barrier) ----
            if (t + 1 < TT) {
                size_t idx2 = idx + HH;
                pxr = st_load(xr + idx2); pxz = st_load(xz + idx2); pxi = out[idx2];
            }
        }
        xbar(ctr, bstep * GBLK); ++bstep;
    }
}

__global__ void sentinel_kernel(float* out) {
    if (threadIdx.x == 0 && blockIdx.x == 0) out[0] = 12345.0f;
}

// =====================================================================
extern "C" void kernel_launch(void* const* d_in, const int* in_sizes, int n_in,
                              void* d_out, int out_size, void* d_ws, size_t ws_size,
                              hipStream_t stream) {
    const float* x   = (const float*)d_in[0];
    const float* Wxr = (const float*)d_in[1];
    const float* Whr = (const float*)d_in[2];
    const float* br  = (const float*)d_in[3];
    const float* Wxz = (const float*)d_in[4];
    const float* Whz = (const float*)d_in[5];
    const float* bz  = (const float*)d_in[6];
    const float* Wi  = (const float*)d_in[7];
    const float* Wh  = (const float*)d_in[8];
    const float* bb  = (const float*)d_in[9];
    float* out = (float*)d_out;

    const size_t BTH = (size_t)BB * TT * HH;
    const size_t HBUF_ELTS = (size_t)2 * BB * HH;
    const size_t BAR_BYTES = 4096;
    const size_t need_f32 = 2 * BTH * sizeof(float) + HBUF_ELTS * sizeof(float) + BAR_BYTES;
    const size_t need_b16 = 2 * BTH * sizeof(__hip_bfloat16) + HBUF_ELTS * sizeof(float) + BAR_BYTES;

    dim3 pgrid(HH / 64, (BB * TT) / 64);   // (16, 256)

    if (ws_size >= need_f32) {
        float* xr = (float*)d_ws;
        float* xz = xr + BTH;
        float* hb = xz + BTH;
        u32* bar = (u32*)(hb + HBUF_ELTS);
        proj_kernel<float><<<pgrid, 256, 0, stream>>>(x, Wxr, br, Wxz, bz, Wi, bb, xr, xz, out, bar);
        const float* xrc = xr; const float* xzc = xz;
        void* args[8] = {(void*)&xrc, (void*)&xzc, (void*)&Whr, (void*)&Whz,
                         (void*)&Wh, (void*)&out, (void*)&hb, (void*)&bar};
        hipLaunchCooperativeKernel((void*)scan_kernel<float>, dim3(256), dim3(512),
                                   args, 0, stream);
    } else if (ws_size >= need_b16) {
        __hip_bfloat16* xr = (__hip_bfloat16*)d_ws;
        __hip_bfloat16* xz = xr + BTH;
        float* hb = (float*)(xz + BTH);
        u32* bar = (u32*)(hb + HBUF_ELTS);
        proj_kernel<__hip_bfloat16><<<pgrid, 256, 0, stream>>>(x, Wxr, br, Wxz, bz, Wi, bb, xr, xz, out, bar);
        const __hip_bfloat16* xrc = xr; const __hip_bfloat16* xzc = xz;
        void* args[8] = {(void*)&xrc, (void*)&xzc, (void*)&Whr, (void*)&Whz,
                         (void*)&Wh, (void*)&out, (void*)&hb, (void*)&bar};
        hipLaunchCooperativeKernel((void*)scan_kernel<__hip_bfloat16>, dim3(256), dim3(512),
                                   args, 0, stream);
    } else {
        sentinel_kernel<<<1, 64, 0, stream>>>(out);
    }
}

// Round 5
// 5154.293 us; speedup vs baseline: 7.4383x; 1.1065x over previous
//
#include <hip/hip_runtime.h>
#include <hip/hip_bf16.h>
#include <cstddef>
#include <cstdint>

static constexpr int BB = 16;    // batch
static constexpr int TT = 1024;  // time steps
static constexpr int EE = 512;   // input dim
static constexpr int HH = 1024;  // hidden dim

// scan decomposition: 4 groups x 64 blocks; group owns 4 batches, all cols.
static constexpr int NG   = 4;    // batch groups
static constexpr int GBLK = 64;   // blocks per group
static constexpr int BPG  = 4;    // batches per group
static constexpr int COLS = 16;   // hidden columns per block

using u32 = unsigned int;
typedef float f32x4 __attribute__((ext_vector_type(4)));

// "not yet written" sentinel for the h-exchange protocol. h is always finite
// (sigmoid/tanh combinations of finite inputs), so a specific NaN payload can
// never be produced as a real value.
static constexpr u32 PZ = 0x7FC0DEADu;

// ---------- storage-type helpers (fp32 or bf16 scratch for xr/xz) ----------
__device__ __forceinline__ float st_load(const float* p) { return *p; }
__device__ __forceinline__ float st_load(const __hip_bfloat16* p) { return __bfloat162float(*p); }
__device__ __forceinline__ void st_store(float* p, float v) { *p = v; }
__device__ __forceinline__ void st_store(__hip_bfloat16* p, float v) { *p = __float2bfloat16(v); }

// 16B device-scope (L1/L2-bypassing, LLC-coherent) load. Batch-issue, then
// drain with llc_drain() — inline-asm loads are NOT compiler-tracked.
__device__ __forceinline__ void llc_load(f32x4& d, const f32x4* p) {
    asm volatile("global_load_dwordx4 %0, %1, off sc0 sc1" : "=v"(d) : "v"(p));
}
__device__ __forceinline__ void llc_drain() {
    asm volatile("s_waitcnt vmcnt(0)" ::: "memory");
    __builtin_amdgcn_sched_barrier(0);
}
__device__ __forceinline__ bool ok4(const f32x4 v) {
    return __float_as_uint(v[0]) != PZ && __float_as_uint(v[1]) != PZ &&
           __float_as_uint(v[2]) != PZ && __float_as_uint(v[3]) != PZ;
}

#define FMA4(ACC, S, W)                         \
    (ACC).x = fmaf((S), (W).x, (ACC).x);        \
    (ACC).y = fmaf((S), (W).y, (ACC).y);        \
    (ACC).z = fmaf((S), (W).z, (ACC).z);        \
    (ACC).w = fmaf((S), (W).w, (ACC).w);

// =====================================================================
// Phase 1: xr = x@Wxr+br -> ws, xz = x@Wxz+bz -> ws, xi = x@Wi+b -> d_out
// Also zeroes the scan kernel's barrier counters (block (0,0)).
// =====================================================================
template <typename ST>
__global__ __launch_bounds__(256) void proj_kernel(
    const float* __restrict__ x,
    const float* __restrict__ Wxr, const float* __restrict__ br,
    const float* __restrict__ Wxz, const float* __restrict__ bz,
    const float* __restrict__ Wi,  const float* __restrict__ bi,
    ST* __restrict__ xr_out, ST* __restrict__ xz_out, float* __restrict__ xi_out,
    u32* __restrict__ bar)
{
    __shared__ float xT[16][68];
    __shared__ float wB[3][16][64];

    const int tid = threadIdx.x;
    if (blockIdx.x == 0 && blockIdx.y == 0) bar[tid] = 0u;   // 1KB of counters

    const int tx = tid & 15, ty = tid >> 4;
    const int m0 = blockIdx.y * 64, n0 = blockIdx.x * 64;
    const float* Wg[3] = {Wxr, Wxz, Wi};

    float4 acc[3][4];
#pragma unroll
    for (int g = 0; g < 3; ++g)
#pragma unroll
        for (int i = 0; i < 4; ++i) acc[g][i] = make_float4(0.f, 0.f, 0.f, 0.f);

    const int xrow = tid >> 2, xk = (tid & 3) * 4;
    const int wk = tid >> 4, wn = (tid & 15) * 4;

    for (int k0 = 0; k0 < EE; k0 += 16) {
        float4 xv = *(const float4*)(x + (size_t)(m0 + xrow) * EE + k0 + xk);
        xT[xk + 0][xrow] = xv.x;
        xT[xk + 1][xrow] = xv.y;
        xT[xk + 2][xrow] = xv.z;
        xT[xk + 3][xrow] = xv.w;
#pragma unroll
        for (int g = 0; g < 3; ++g) {
            float4 wv = *(const float4*)(Wg[g] + (size_t)(k0 + wk) * HH + n0 + wn);
            *(float4*)&wB[g][wk][wn] = wv;
        }
        __syncthreads();
#pragma unroll
        for (int kk = 0; kk < 16; ++kk) {
            float4 a  = *(const float4*)&xT[kk][ty * 4];
            float4 w0 = *(const float4*)&wB[0][kk][tx * 4];
            float4 w1 = *(const float4*)&wB[1][kk][tx * 4];
            float4 w2 = *(const float4*)&wB[2][kk][tx * 4];
            float as[4] = {a.x, a.y, a.z, a.w};
#pragma unroll
            for (int i = 0; i < 4; ++i) {
                FMA4(acc[0][i], as[i], w0);
                FMA4(acc[1][i], as[i], w1);
                FMA4(acc[2][i], as[i], w2);
            }
        }
        __syncthreads();
    }

    float4 bv0 = *(const float4*)(br + n0 + tx * 4);
    float4 bv1 = *(const float4*)(bz + n0 + tx * 4);
    float4 bv2 = *(const float4*)(bi + n0 + tx * 4);
#pragma unroll
    for (int i = 0; i < 4; ++i) {
        size_t m = (size_t)m0 + ty * 4 + i;
        size_t off = m * HH + n0 + tx * 4;
        float4 v0 = acc[0][i]; v0.x += bv0.x; v0.y += bv0.y; v0.z += bv0.z; v0.w += bv0.w;
        float4 v1 = acc[1][i]; v1.x += bv1.x; v1.y += bv1.y; v1.z += bv1.z; v1.w += bv1.w;
        float4 v2 = acc[2][i]; v2.x += bv2.x; v2.y += bv2.y; v2.z += bv2.z; v2.w += bv2.w;
        st_store(xr_out + off + 0, v0.x); st_store(xr_out + off + 1, v0.y);
        st_store(xr_out + off + 2, v0.z); st_store(xr_out + off + 3, v0.w);
        st_store(xz_out + off + 0, v1.x); st_store(xz_out + off + 1, v1.y);
        st_store(xz_out + off + 2, v1.z); st_store(xz_out + off + 3, v1.w);
        *(float4*)(xi_out + off) = v2;
    }
}

// =====================================================================
// DPP all-reduce over each row of 16 lanes (sum).
// =====================================================================
__device__ __forceinline__ float row16_allreduce(float v) {
    int y;
    y = __builtin_amdgcn_update_dpp(0, __float_as_int(v), 0xB1, 0xF, 0xF, true);  // quad_perm [1,0,3,2]
    v += __int_as_float(y);
    y = __builtin_amdgcn_update_dpp(0, __float_as_int(v), 0x4E, 0xF, 0xF, true);  // quad_perm [2,3,0,1]
    v += __int_as_float(y);
    y = __builtin_amdgcn_update_dpp(0, __float_as_int(v), 0x124, 0xF, 0xF, true); // row_ror:4
    v += __int_as_float(y);
    y = __builtin_amdgcn_update_dpp(0, __float_as_int(v), 0x128, 0xF, 0xF, true); // row_ror:8
    v += __int_as_float(y);
    return v;
}

// =====================================================================
// One-time flat per-group barrier (relaxed agent-scope atomics). Used only
// to order the h-buffer zero/poison initialization before the main loop;
// the loop itself is barrier-free (data-driven sentinel protocol).
// =====================================================================
__device__ __forceinline__ void xbar(u32* ctr, unsigned target) {
    __syncthreads();
    if (threadIdx.x == 0) {
        asm volatile("s_waitcnt vmcnt(0)" ::: "memory");
        __builtin_amdgcn_sched_barrier(0);
        __hip_atomic_fetch_add(ctr, 1u, __ATOMIC_RELAXED, __HIP_MEMORY_SCOPE_AGENT);
        while (__hip_atomic_load(ctr, __ATOMIC_RELAXED, __HIP_MEMORY_SCOPE_AGENT) < target) {
            __builtin_amdgcn_s_sleep(1);
        }
        __builtin_amdgcn_sched_barrier(0);
    }
    __syncthreads();
}

// =====================================================================
// Phase 2: persistent scan, barrier-free. 4 groups x 64 blocks x 512 thr.
// h exchange via 4 rotating LLC buffers with NaN-sentinel ("data is the
// signal"): producers store real values; consumers poll until non-poison.
// Safety of re-poisoning B(t+2) at step t: a block at step t has read all
// of h_t => every block stored h_t => every block passed step t-1 entirely
// => all reads of B(t+2)'s previous epoch (h_{t-2}) are complete. The
// vmcnt(0) drain before each h-store orders poison < h-store globally.
// Per-wave decoupling: wave wv polls only its own 128-slot k-slice and
// stages it in its private LDS region (wave-local lgkmcnt sync) — a wave
// starts its FMAs as soon as ITS 8 producer blocks have stored.
// =====================================================================
template <typename ST>
__global__ __launch_bounds__(512, 1) void scan_kernel(
    const ST* __restrict__ xr, const ST* __restrict__ xz,
    const float* __restrict__ Whr, const float* __restrict__ Whz, const float* __restrict__ Wh,
    float* __restrict__ out,      // d_out: holds xi pre-activations, overwritten with h
    float* __restrict__ hbuf,     // [4][16][1024] fp32 rotating exchange buffers
    u32* __restrict__ bar)
{
    __shared__ f32x4 hsx[8][4][32];      // [wave][batch][slot] 16KB, wave-private regions
    __shared__ float red[8][4][48];      // [wave][cgg][b4*12+u]
    __shared__ float pre[48][4];         // [gate*16+col][b4]

    const int tid = threadIdx.x, bid = blockIdx.x;
    const int lane = tid & 63, wv = tid >> 6;       // wv 0..7
    const int cgg = lane >> 4, kslo = lane & 15;
    const int ks = wv * 16 + kslo;                  // 0..127
    const int group = bid >> 6, gb = bid & 63;
    const int n0 = gb * COLS;                       // global column base
    u32* ctr = bar + group * 64;

    // ---- recurrent weights -> registers (one-time): 12 units x 8 k ----
    float wreg[12][8];
    {
        const float* WG[3] = {Whr, Whz, Wh};
#pragma unroll
        for (int u = 0; u < 12; ++u) {
            int ugc = cgg * 12 + u;                 // 0..47: gate=ugc>>4, col=ugc&15
            const float* W = WG[ugc >> 4];
            int col = n0 + (ugc & 15);
#pragma unroll
            for (int j = 0; j < 8; ++j)
                wreg[u][j] = W[(size_t)(ks * 8 + j) * HH + col];
        }
    }

    const float pzf = __uint_as_float(PZ);
    const int tb4 = tid >> 4, tc = tid & 15;        // elementwise mapping (tid<64)
    const int tbg = group * BPG + tb4;              // global batch
    const int coln = n0 + tc;

    // ---- init: zero B0 (h_0 = 0), poison B1..B3; prefetch t=0 operands ----
    float pxr = 0.f, pxz = 0.f, pxi = 0.f, hprev = 0.f;
    if (tid < 64) {
        float* b0 = hbuf + group * (BPG * HH) + tb4 * HH + coln;
        __hip_atomic_store(b0,           0.f, __ATOMIC_RELAXED, __HIP_MEMORY_SCOPE_AGENT);
        __hip_atomic_store(b0 + 16384,   pzf, __ATOMIC_RELAXED, __HIP_MEMORY_SCOPE_AGENT);
        __hip_atomic_store(b0 + 32768,   pzf, __ATOMIC_RELAXED, __HIP_MEMORY_SCOPE_AGENT);
        __hip_atomic_store(b0 + 49152,   pzf, __ATOMIC_RELAXED, __HIP_MEMORY_SCOPE_AGENT);
        size_t idx0 = (size_t)(tbg * TT) * HH + coln;
        pxr = st_load(xr + idx0); pxz = st_load(xz + idx0); pxi = out[idx0];
    }
    xbar(ctr, GBLK);   // one-time: init visible before anyone polls

    // staging assignment: lane loads 2 adjacent slots of wave's 32-slot
    // window (per its batch), rotated by gb to spread LLC banks.
    const int b_ld = lane >> 4;
    const int s_rot = (((lane & 15) + (gb & 15)) * 2) & 31;   // even, in [0,32)

    for (int t = 0; t < TT; ++t) {
        // ---- stage h_t: poll own k-slice until non-poison, wave-local sync ----
        {
            const f32x4* p = (const f32x4*)hbuf + (size_t)(t & 3) * 4096
                             + group * 1024 + b_ld * 256 + wv * 32 + s_rot;
            f32x4 va, vb;
            for (;;) {
                llc_load(va, p); llc_load(vb, p + 1); llc_drain();
                if (ok4(va) && ok4(vb)) break;
                __builtin_amdgcn_s_sleep(1);
            }
            hsx[wv][b_ld][s_rot]     = va;
            hsx[wv][b_ld][s_rot + 1] = vb;
            asm volatile("s_waitcnt lgkmcnt(0)" ::: "memory");  // wave-local LDS visibility
            __builtin_amdgcn_sched_barrier(0);
        }

        // ---- partial dots: 4 batches x 12 units x 8 k = 384 FMA/thread ----
        float pacc[4][12];
#pragma unroll
        for (int b = 0; b < 4; ++b)
#pragma unroll
            for (int u = 0; u < 12; ++u) pacc[b][u] = 0.f;

#pragma unroll
        for (int b = 0; b < 4; ++b) {
            f32x4 ha = hsx[wv][b][2 * kslo];
            f32x4 hb = hsx[wv][b][2 * kslo + 1];
#pragma unroll
            for (int u = 0; u < 12; ++u) {
                float a = pacc[b][u];
                a = fmaf(ha[0], wreg[u][0], a);
                a = fmaf(ha[1], wreg[u][1], a);
                a = fmaf(ha[2], wreg[u][2], a);
                a = fmaf(ha[3], wreg[u][3], a);
                a = fmaf(hb[0], wreg[u][4], a);
                a = fmaf(hb[1], wreg[u][5], a);
                a = fmaf(hb[2], wreg[u][6], a);
                a = fmaf(hb[3], wreg[u][7], a);
                pacc[b][u] = a;
            }
        }

        // ---- reduce over kslo (16 lanes per row) ----
#pragma unroll
        for (int b = 0; b < 4; ++b)
#pragma unroll
            for (int u = 0; u < 12; ++u) pacc[b][u] = row16_allreduce(pacc[b][u]);

        if (kslo == 0) {
#pragma unroll
            for (int b = 0; b < 4; ++b)
#pragma unroll
                for (int u = 0; u < 12; ++u) red[wv][cgg][b * 12 + u] = pacc[b][u];
        }

        // ---- re-poison B(t+2) (in flight through S1+combine+S2) ----
        if (tid < 64 && t + 2 < TT) {
            __hip_atomic_store(hbuf + (size_t)((t + 2) & 3) * 16384
                               + group * (BPG * HH) + tb4 * HH + coln,
                               pzf, __ATOMIC_RELAXED, __HIP_MEMORY_SCOPE_AGENT);
        }
        __syncthreads();                 // S1: red ready

        // ---- combine 8 waves -> 192 gate pre-activations ----
        if (tid < 192) {
            int b4 = tid & 3, ugc = tid >> 2;        // ugc in [0,48)
            int cq = ugc / 12, u = ugc - cq * 12;
            float s = 0.f;
#pragma unroll
            for (int w = 0; w < 8; ++w) s += red[w][cq][b4 * 12 + u];
            pre[ugc][b4] = s;
        }
        __syncthreads();                 // S2: pre ready

        // ---- elementwise GRU update; h-store is the next step's signal ----
        if (tid < 64) {
            float dr = pre[tc][tb4], dz = pre[16 + tc][tb4], dh = pre[32 + tc][tb4];
            float r = 1.f / (1.f + expf(-(dr + pxr)));
            float z = 1.f / (1.f + expf(-(dz + pxz)));
            float cand = tanhf(fmaf(r, dh, pxi));
            float hnew = fmaf(z, hprev - cand, cand);         // z*h + (1-z)*cand
            hprev = hnew;                                     // carried in register
            // order poison (and all prior vmem) before the h release-store
            asm volatile("s_waitcnt vmcnt(0)" ::: "memory");
            __builtin_amdgcn_sched_barrier(0);
            if (t + 1 < TT) {
                __hip_atomic_store(hbuf + (size_t)((t + 1) & 3) * 16384
                                   + group * (BPG * HH) + tb4 * HH + coln,
                                   hnew, __ATOMIC_RELAXED, __HIP_MEMORY_SCOPE_AGENT);
            }
            size_t idx = (size_t)(tbg * TT + t) * HH + coln;
            out[idx] = hnew;
            // self-prefetch t+1 operands (off critical path; lands during next step)
            if (t + 1 < TT) {
                size_t idx2 = idx + HH;
                pxr = st_load(xr + idx2); pxz = st_load(xz + idx2); pxi = out[idx2];
            }
        }
        // no barrier: waves proceed straight to polling h_{t+1}
    }
}

__global__ void sentinel_kernel(float* out) {
    if (threadIdx.x == 0 && blockIdx.x == 0) out[0] = 12345.0f;
}

// =====================================================================
extern "C" void kernel_launch(void* const* d_in, const int* in_sizes, int n_in,
                              void* d_out, int out_size, void* d_ws, size_t ws_size,
                              hipStream_t stream) {
    const float* x   = (const float*)d_in[0];
    const float* Wxr = (const float*)d_in[1];
    const float* Whr = (const float*)d_in[2];
    const float* br  = (const float*)d_in[3];
    const float* Wxz = (const float*)d_in[4];
    const float* Whz = (const float*)d_in[5];
    const float* bz  = (const float*)d_in[6];
    const float* Wi  = (const float*)d_in[7];
    const float* Wh  = (const float*)d_in[8];
    const float* bb  = (const float*)d_in[9];
    float* out = (float*)d_out;

    const size_t BTH = (size_t)BB * TT * HH;
    const size_t HBUF_ELTS = (size_t)4 * BB * HH;      // 4 rotating buffers
    const size_t BAR_BYTES = 4096;
    const size_t need_f32 = 2 * BTH * sizeof(float) + HBUF_ELTS * sizeof(float) + BAR_BYTES;
    const size_t need_b16 = 2 * BTH * sizeof(__hip_bfloat16) + HBUF_ELTS * sizeof(float) + BAR_BYTES;

    dim3 pgrid(HH / 64, (BB * TT) / 64);   // (16, 256)

    if (ws_size >= need_f32) {
        float* xr = (float*)d_ws;
        float* xz = xr + BTH;
        float* hb = xz + BTH;
        u32* bar = (u32*)(hb + HBUF_ELTS);
        proj_kernel<float><<<pgrid, 256, 0, stream>>>(x, Wxr, br, Wxz, bz, Wi, bb, xr, xz, out, bar);
        const float* xrc = xr; const float* xzc = xz;
        void* args[8] = {(void*)&xrc, (void*)&xzc, (void*)&Whr, (void*)&Whz,
                         (void*)&Wh, (void*)&out, (void*)&hb, (void*)&bar};
        hipLaunchCooperativeKernel((void*)scan_kernel<float>, dim3(256), dim3(512),
                                   args, 0, stream);
    } else if (ws_size >= need_b16) {
        __hip_bfloat16* xr = (__hip_bfloat16*)d_ws;
        __hip_bfloat16* xz = xr + BTH;
        float* hb = (float*)(xz + BTH);
        u32* bar = (u32*)(hb + HBUF_ELTS);
        proj_kernel<__hip_bfloat16><<<pgrid, 256, 0, stream>>>(x, Wxr, br, Wxz, bz, Wi, bb, xr, xz, out, bar);
        const __hip_bfloat16* xrc = xr; const __hip_bfloat16* xzc = xz;
        void* args[8] = {(void*)&xrc, (void*)&xzc, (void*)&Whr, (void*)&Whz,
                         (void*)&Wh, (void*)&out, (void*)&hb, (void*)&bar};
        hipLaunchCooperativeKernel((void*)scan_kernel<__hip_bfloat16>, dim3(256), dim3(512),
                                   args, 0, stream);
    } else {
        sentinel_kernel<<<1, 64, 0, stream>>>(out);
    }
}